// Round 2
// baseline (32999.744 us; speedup 1.0000x reference)
//
#include <hip/hip_runtime.h>
#include <math.h>
#include <stdint.h>

#define T_SEQ 4096

__device__ __forceinline__ float sigm(float x) { return 1.0f / (1.0f + expf(-x)); }

// ---------------------------------------------------------------------------
// fp32 NT GEMM with bias: layer-0 preactivations for both branches.
// C[m][p(j)] = sum_k A[m][k]*B[j][k] + bias1[j]+bias2[j]
// Column permutation p(j): j = gate*1024 + 4b+u  ->  b*16 + gate*4 + u, so
// each recurrence block's 16 gate preacts are one contiguous 64 B line.
// ---------------------------------------------------------------------------
__global__ void __launch_bounds__(256) gemm_nt_bias(
    const float* __restrict__ A0, const float* __restrict__ A1,
    const float* __restrict__ B,
    const float* __restrict__ bias1, const float* __restrict__ bias2,
    float* __restrict__ C)
{
    const int t  = threadIdx.x;
    const int tx = t & 15, ty = t >> 4;
    const int n0 = blockIdx.x * 128, m0 = blockIdx.y * 128;
    const float* Ab = (m0 < 4096) ? A0 : A1;
    const int ml0 = (m0 < 4096) ? m0 : (m0 - 4096);

    __shared__ float As[16 * 140];
    __shared__ float Bs[16 * 140];

    const int lr = t >> 1;
    const int lh = t & 1;
    const int pw = lr + ((lr >> 5) << 2);
    const int pa = ty * 8 + ((ty >> 2) << 2);
    const int pb = tx * 8 + ((tx >> 2) << 2);

    float acc[8][8];
#pragma unroll
    for (int i = 0; i < 8; ++i)
#pragma unroll
        for (int j = 0; j < 8; ++j) acc[i][j] = 0.f;

    for (int k0 = 0; k0 < 1024; k0 += 16) {
        const float* ap = Ab + (size_t)(ml0 + lr) * 1024 + k0 + lh * 8;
        float4 av0 = *(const float4*)ap;
        float4 av1 = *(const float4*)(ap + 4);
        const float* bp = B + (size_t)(n0 + lr) * 1024 + k0 + lh * 8;
        float4 bv0 = *(const float4*)bp;
        float4 bv1 = *(const float4*)(bp + 4);

        __syncthreads();
        const int kb = lh * 8;
        As[(kb + 0) * 140 + pw] = av0.x;  As[(kb + 1) * 140 + pw] = av0.y;
        As[(kb + 2) * 140 + pw] = av0.z;  As[(kb + 3) * 140 + pw] = av0.w;
        As[(kb + 4) * 140 + pw] = av1.x;  As[(kb + 5) * 140 + pw] = av1.y;
        As[(kb + 6) * 140 + pw] = av1.z;  As[(kb + 7) * 140 + pw] = av1.w;
        Bs[(kb + 0) * 140 + pw] = bv0.x;  Bs[(kb + 1) * 140 + pw] = bv0.y;
        Bs[(kb + 2) * 140 + pw] = bv0.z;  Bs[(kb + 3) * 140 + pw] = bv0.w;
        Bs[(kb + 4) * 140 + pw] = bv1.x;  Bs[(kb + 5) * 140 + pw] = bv1.y;
        Bs[(kb + 6) * 140 + pw] = bv1.z;  Bs[(kb + 7) * 140 + pw] = bv1.w;
        __syncthreads();

#pragma unroll
        for (int kk = 0; kk < 16; ++kk) {
            float4 a0 = *(const float4*)&As[kk * 140 + pa];
            float4 a1 = *(const float4*)&As[kk * 140 + pa + 4];
            float4 b0 = *(const float4*)&Bs[kk * 140 + pb];
            float4 b1 = *(const float4*)&Bs[kk * 140 + pb + 4];
            float a[8]  = {a0.x, a0.y, a0.z, a0.w, a1.x, a1.y, a1.z, a1.w};
            float bb[8] = {b0.x, b0.y, b0.z, b0.w, b1.x, b1.y, b1.z, b1.w};
#pragma unroll
            for (int i = 0; i < 8; ++i)
#pragma unroll
                for (int j = 0; j < 8; ++j)
                    acc[i][j] = fmaf(a[i], bb[j], acc[i][j]);
        }
    }

    const int gcol  = n0 >> 10;              // gate for this whole block-column
    const int qbase = (n0 & 1023) + tx * 8;  // 4b+u base
    const int j0 = n0 + tx * 8;
    float bsv[8];
#pragma unroll
    for (int j = 0; j < 8; ++j) bsv[j] = bias1[j0 + j] + bias2[j0 + j];
#pragma unroll
    for (int i = 0; i < 8; ++i) {
        const size_t rowoff = (size_t)(m0 + ty * 8 + i) * 4096;
#pragma unroll
        for (int jj = 0; jj < 8; ++jj) {
            const int q = qbase + jj;
            C[rowoff + ((q >> 2) << 4) + (gcol << 2) + (q & 3)] = acc[i][jj] + bsv[jj];
        }
    }
}

// ---------------------------------------------------------------------------
// Fused layer-pipelined LSTM recurrence.
// 256 blocks x 256 threads, PLAIN launch (no cooperative API needed):
// __launch_bounds__(256,1) guarantees >=1 block/CU occupancy, and with 256
// blocks on 256 CUs all blocks are co-resident, so the tag spin-waits make
// progress. Tick tau: layer0 step tau, layer1 step tau-1.
//
// BARRIER-FREE DATAFLOW: every h element travels as one 64-bit word
// (tag<<32 | float_bits) via relaxed agent-scope atomics (LLC-coherent on
// gfx950, proven by prior sessions). Consumers poll the tag; the readiness
// check and the data arrive in the SAME load, so h transport costs exactly
// one store->load LLC round trip instead of the old chain
// (vmcnt drain -> arrival RT -> release RT -> h load RT).
//
// Ring-of-2 safety: slot written at end of tick tau carries tag tau+2 and
// is consumed at tick tau+1 (want = tick+1). A slot is only overwritten
// (tag +2) after its writer finished staging the previous tick, which
// requires every block to have finished consuming the slot -> skew < 2
// ticks, no ABA (tags are monotonic per slot within a run; the in-stream
// memset re-zeroes tags before every replay). Tags start at 1 (init h into
// buffer1) and 2 (layer-1 init into buffer0).
// ---------------------------------------------------------------------------
__global__ void __launch_bounds__(256, 1) lstm_fused(
    const float* __restrict__ W_hh,  // [2][4096][1024]
    const float* __restrict__ W_ih,  // [2][4096][1024]
    const float* __restrict__ b_ih,  // [2][4096]
    const float* __restrict__ b_hh,  // [2][4096]
    const float* __restrict__ G,     // [2 br][T][4096] permuted layer-0 preacts
    const float* __restrict__ h1_0, const float* __restrict__ c1_0,
    const float* __restrict__ h2_0, const float* __restrict__ c2_0,
    uint64_t* hb)                    // [2 buf][4096] tagged h ring (low 8KB doubles as o_out)
{
    const int b = blockIdx.x, t = threadIdx.x;
    const int row = t & 15, slice = t >> 4;
    const int gate = row >> 2, uoff = row & 3;
    const int j_glob = gate * 1024 + b * 4 + uoff;

    // ---- weights -> registers (rotated to match LDS traversal) ----
    float4 w0[16], w1h[16], w1i[16];
    {
        const float* r0 = W_hh + (size_t)j_glob * 1024 + slice * 64;
        const float* r1 = W_hh + 4194304ull + (size_t)j_glob * 1024 + slice * 64;
        const float* r2 = W_ih + 4194304ull + (size_t)j_glob * 1024 + slice * 64;
#pragma unroll
        for (int m = 0; m < 16; ++m) {
            const int o = ((m + slice) & 15) << 2;
            w0[m]  = *(const float4*)(r0 + o);
            w1h[m] = *(const float4*)(r1 + o);
            w1i[m] = *(const float4*)(r2 + o);
        }
    }

    __shared__ float hs[4096];        // [4 vec][1024]
    __shared__ float red[4][4][16];   // [wave][acc][row]
    __shared__ float bl1s[16];        // layer-1 bias for owned rows

    float creg = 0.f;
    if (t < 16) {
        const int layer = t >> 3, br = (t >> 2) & 1, u = t & 3;
        const float* cc = br ? c2_0 : c1_0;
        const float* hh = br ? h2_0 : h1_0;
        creg = cc[layer * 1024 + b * 4 + u];
        const float hinit = hh[layer * 1024 + b * 4 + u];
        const uint64_t hbits = (uint64_t)__float_as_uint(hinit);
        // init h -> buffer1 (consumed at tick 0, want=1)
        __hip_atomic_store(hb + 4096 + layer * 2048 + br * 1024 + b * 4 + u,
                           (1ull << 32) | hbits,
                           __ATOMIC_RELAXED, __HIP_MEMORY_SCOPE_AGENT);
        // layer-1 init also -> buffer0 (consumed at tick 1, want=2);
        // layer-1 is inactive at tick 0 so nothing else writes this slot.
        if (layer == 1)
            __hip_atomic_store(hb + 2048 + br * 1024 + b * 4 + u,
                               (2ull << 32) | hbits,
                               __ATOMIC_RELAXED, __HIP_MEMORY_SCOPE_AGENT);
    }
    if (t >= 32 && t < 48) {
        const int rr = t & 15;
        const int jj = 4096 + (rr >> 2) * 1024 + b * 4 + (rr & 3);
        bl1s[rr] = b_ih[jj] + b_hh[jj];
    }
    __syncthreads();

    for (int tick = 0; tick <= T_SEQ; ++tick) {
        // ---- layer-0 G prefetch first (latency hidden under the h poll) ----
        float gpre = 0.f;
        if (t < 32) {
            const int br = t >> 4, rr = t & 15;
            const int st = (tick < T_SEQ) ? tick : (T_SEQ - 1);
            gpre = G[((size_t)br * T_SEQ + st) * 4096 + b * 16 + rr];
        }

        // ---- stage h_prev: poll tagged slots; data rides with the tag ----
        {
            const uint64_t* src = hb + ((tick + 1) & 1) * 4096;
            const uint32_t want = (uint32_t)tick + 1u;
            uint64_t v[16];
#pragma unroll
            for (int r = 0; r < 16; ++r)
                v[r] = __hip_atomic_load(src + t + r * 256, __ATOMIC_RELAXED,
                                         __HIP_MEMORY_SCOPE_AGENT);
#pragma unroll
            for (int r = 0; r < 16; ++r) {
                uint64_t x = v[r];
                while ((uint32_t)(x >> 32) != want) {
                    __builtin_amdgcn_s_sleep(1);
                    x = __hip_atomic_load(src + t + r * 256, __ATOMIC_RELAXED,
                                          __HIP_MEMORY_SCOPE_AGENT);
                }
                hs[t + r * 256] = __uint_as_float((uint32_t)x);
            }
        }
        __syncthreads();

        // ---- 3 matvecs over owned rows ----
        float a00 = 0.f, a01 = 0.f, a10 = 0.f, a11 = 0.f;
        const float4* H00 = (const float4*)hs;
        const float4* H01 = (const float4*)(hs + 1024);
        const float4* H10 = (const float4*)(hs + 2048);
        const float4* H11 = (const float4*)(hs + 3072);
#pragma unroll
        for (int m = 0; m < 16; ++m) {
            const int ci = (slice << 4) + ((m + slice) & 15);
            const float4 x0 = H00[ci], x1 = H01[ci];
            const float4 y0 = H10[ci], y1 = H11[ci];
            a00 = fmaf(w0[m].x, x0.x, a00); a00 = fmaf(w0[m].y, x0.y, a00);
            a00 = fmaf(w0[m].z, x0.z, a00); a00 = fmaf(w0[m].w, x0.w, a00);
            a01 = fmaf(w0[m].x, x1.x, a01); a01 = fmaf(w0[m].y, x1.y, a01);
            a01 = fmaf(w0[m].z, x1.z, a01); a01 = fmaf(w0[m].w, x1.w, a01);
            a10 = fmaf(w1i[m].x, x0.x, a10); a10 = fmaf(w1i[m].y, x0.y, a10);
            a10 = fmaf(w1i[m].z, x0.z, a10); a10 = fmaf(w1i[m].w, x0.w, a10);
            a10 = fmaf(w1h[m].x, y0.x, a10); a10 = fmaf(w1h[m].y, y0.y, a10);
            a10 = fmaf(w1h[m].z, y0.z, a10); a10 = fmaf(w1h[m].w, y0.w, a10);
            a11 = fmaf(w1i[m].x, x1.x, a11); a11 = fmaf(w1i[m].y, x1.y, a11);
            a11 = fmaf(w1i[m].z, x1.z, a11); a11 = fmaf(w1i[m].w, x1.w, a11);
            a11 = fmaf(w1h[m].x, y1.x, a11); a11 = fmaf(w1h[m].y, y1.y, a11);
            a11 = fmaf(w1h[m].w, y1.w, a11); a11 = fmaf(w1h[m].z, y1.z, a11);
        }
        a00 += __shfl_xor(a00, 16); a00 += __shfl_xor(a00, 32);
        a01 += __shfl_xor(a01, 16); a01 += __shfl_xor(a01, 32);
        a10 += __shfl_xor(a10, 16); a10 += __shfl_xor(a10, 32);
        a11 += __shfl_xor(a11, 16); a11 += __shfl_xor(a11, 32);
        const int wv = t >> 6, lane = t & 63;
        if (lane < 16) {
            red[wv][0][lane] = a00; red[wv][1][lane] = a01;
            red[wv][2][lane] = a10; red[wv][3][lane] = a11;
        }
        __syncthreads();

        // ---- tail: wave 0 only (red[] reuse is safe: other waves' next
        //      red-write sits behind the next post-staging __syncthreads,
        //      which waits for wave 0 to finish this tail) ----
        if (t < 64) {
            const int lb = t >> 4, rr = t & 15;
            float s = red[0][lb][rr] + red[1][lb][rr] + red[2][lb][rr] + red[3][lb][rr];
            s += (lb < 2) ? gpre : bl1s[rr];
            // lane lb*16+rr holds gate (rr>>2) of unit (rr&3), layer=lb>>1, br=lb&1
            const int src0 = ((t >> 2) << 4) + (t & 3);   // meaningful for t<16
            const float gi = __shfl(s, src0);
            const float gf = __shfl(s, src0 + 4);
            const float gg = __shfl(s, src0 + 8);
            const float go = __shfl(s, src0 + 12);
            if (t < 16) {
                const int layer = t >> 3, br = (t >> 2) & 1, u = t & 3;
                const bool active = (layer == 0) ? (tick < T_SEQ) : (tick >= 1);
                if (active) {
                    const float c = sigm(gf) * creg + sigm(gi) * tanhf(gg);
                    const float h = sigm(go) * tanhf(c);
                    creg = c;
                    if (layer == 1 && tick == T_SEQ) {
                        // final output -> dead low 8KB of the ring (buffer0/
                        // layer0/br0 slots; no block stages buffer0 after
                        // tick T_SEQ-1, and seeing all tags==T_SEQ+1 at our
                        // tick-T_SEQ staging proves every block finished its
                        // buffer0 reads). Same agent-scope atomic path as
                        // every other h store.
                        __hip_atomic_store((uint32_t*)hb + br * 1024 + b * 4 + u,
                                           __float_as_uint(h),
                                           __ATOMIC_RELAXED, __HIP_MEMORY_SCOPE_AGENT);
                    } else {
                        const uint64_t pv =
                            ((uint64_t)(uint32_t)(tick + 2) << 32) |
                            (uint64_t)__float_as_uint(h);
                        __hip_atomic_store(
                            hb + (tick & 1) * 4096 + layer * 2048 + br * 1024 + b * 4 + u,
                            pv, __ATOMIC_RELAXED, __HIP_MEMORY_SCOPE_AGENT);
                    }
                }
            }
        }
        // no end-of-loop barrier needed: this tick's hs reads completed
        // before the red-barrier above; next staging may overwrite hs freely.
    }
}

// ---------------------------------------------------------------------------
// out = 5*exp(-sum |o1 - o2|)
// ---------------------------------------------------------------------------
__global__ void __launch_bounds__(256) dist_kernel(const float* __restrict__ o,
                                                   float* __restrict__ out)
{
    int t = threadIdx.x;
    float s = 0.f;
    for (int i = t; i < 1024; i += 256) s += fabsf(o[i] - o[i + 1024]);
#pragma unroll
    for (int off = 1; off < 64; off <<= 1) s += __shfl_xor(s, off);
    __shared__ float r[4];
    if ((t & 63) == 0) r[t >> 6] = s;
    __syncthreads();
    if (t == 0) out[0] = 5.0f * expf(-(r[0] + r[1] + r[2] + r[3]));
}

// ---------------------------------------------------------------------------
extern "C" void kernel_launch(void* const* d_in, const int* in_sizes, int n_in,
                              void* d_out, int out_size, void* d_ws, size_t ws_size,
                              hipStream_t stream) {
    const float* s1   = (const float*)d_in[0];
    const float* s2   = (const float*)d_in[1];
    const float* h1_0 = (const float*)d_in[2];
    const float* c1_0 = (const float*)d_in[3];
    const float* h2_0 = (const float*)d_in[4];
    const float* c2_0 = (const float*)d_in[5];
    const float* W_ih = (const float*)d_in[6];
    const float* W_hh = (const float*)d_in[7];
    const float* b_ih = (const float*)d_in[8];
    const float* b_hh = (const float*)d_in[9];

    uint8_t* w8 = (uint8_t*)d_ws;
    uint64_t* hb = (uint64_t*)w8;                // 64 KB: [2][4096] tagged h ring
                                                 //   (low 8 KB reused as o_out)
    float* G     = (float*)(w8 + 65536);         // 128 MB: [2][T][4096]

    hipMemsetAsync(d_ws, 0, 65536, stream);      // zero all ring tags

    // Phase 1: layer-0 input GEMM for both branches (permuted output)
    dim3 ggrid(32, 64);
    gemm_nt_bias<<<ggrid, 256, 0, stream>>>(s1, s2, W_ih, b_ih, b_hh, G);

    // Phase 2: fused recurrence — PLAIN launch; co-residency guaranteed by
    // __launch_bounds__(256,1) with 256 blocks on 256 CUs.
    lstm_fused<<<dim3(256), dim3(256), 0, stream>>>(
        W_hh, W_ih, b_ih, b_hh, G, h1_0, c1_0, h2_0, c2_0, hb);

    // Phase 3: scalar output
    dist_kernel<<<1, 256, 0, stream>>>((const float*)d_ws, (float*)d_out);
}

// Round 3
// 29113.113 us; speedup vs baseline: 1.1335x; 1.1335x over previous
//
#include <hip/hip_runtime.h>
#include <math.h>
#include <stdint.h>

#define T_SEQ 4096

__device__ __forceinline__ float sigm(float x) { return 1.0f / (1.0f + expf(-x)); }

// ---------------------------------------------------------------------------
// fp32 NT GEMM with bias: layer-0 preactivations for both branches.
// C[m][p(j)] = sum_k A[m][k]*B[j][k] + bias1[j]+bias2[j]
// Column permutation p(j): j = gate*1024 + 4b+u  ->  b*16 + gate*4 + u, so
// each recurrence block's 16 gate preacts are one contiguous 64 B line.
// ---------------------------------------------------------------------------
__global__ void __launch_bounds__(256) gemm_nt_bias(
    const float* __restrict__ A0, const float* __restrict__ A1,
    const float* __restrict__ B,
    const float* __restrict__ bias1, const float* __restrict__ bias2,
    float* __restrict__ C)
{
    const int t  = threadIdx.x;
    const int tx = t & 15, ty = t >> 4;
    const int n0 = blockIdx.x * 128, m0 = blockIdx.y * 128;
    const float* Ab = (m0 < 4096) ? A0 : A1;
    const int ml0 = (m0 < 4096) ? m0 : (m0 - 4096);

    __shared__ float As[16 * 140];
    __shared__ float Bs[16 * 140];

    const int lr = t >> 1;
    const int lh = t & 1;
    const int pw = lr + ((lr >> 5) << 2);
    const int pa = ty * 8 + ((ty >> 2) << 2);
    const int pb = tx * 8 + ((tx >> 2) << 2);

    float acc[8][8];
#pragma unroll
    for (int i = 0; i < 8; ++i)
#pragma unroll
        for (int j = 0; j < 8; ++j) acc[i][j] = 0.f;

    for (int k0 = 0; k0 < 1024; k0 += 16) {
        const float* ap = Ab + (size_t)(ml0 + lr) * 1024 + k0 + lh * 8;
        float4 av0 = *(const float4*)ap;
        float4 av1 = *(const float4*)(ap + 4);
        const float* bp = B + (size_t)(n0 + lr) * 1024 + k0 + lh * 8;
        float4 bv0 = *(const float4*)bp;
        float4 bv1 = *(const float4*)(bp + 4);

        __syncthreads();
        const int kb = lh * 8;
        As[(kb + 0) * 140 + pw] = av0.x;  As[(kb + 1) * 140 + pw] = av0.y;
        As[(kb + 2) * 140 + pw] = av0.z;  As[(kb + 3) * 140 + pw] = av0.w;
        As[(kb + 4) * 140 + pw] = av1.x;  As[(kb + 5) * 140 + pw] = av1.y;
        As[(kb + 6) * 140 + pw] = av1.z;  As[(kb + 7) * 140 + pw] = av1.w;
        Bs[(kb + 0) * 140 + pw] = bv0.x;  Bs[(kb + 1) * 140 + pw] = bv0.y;
        Bs[(kb + 2) * 140 + pw] = bv0.z;  Bs[(kb + 3) * 140 + pw] = bv0.w;
        Bs[(kb + 4) * 140 + pw] = bv1.x;  Bs[(kb + 5) * 140 + pw] = bv1.y;
        Bs[(kb + 6) * 140 + pw] = bv1.z;  Bs[(kb + 7) * 140 + pw] = bv1.w;
        __syncthreads();

#pragma unroll
        for (int kk = 0; kk < 16; ++kk) {
            float4 a0 = *(const float4*)&As[kk * 140 + pa];
            float4 a1 = *(const float4*)&As[kk * 140 + pa + 4];
            float4 b0 = *(const float4*)&Bs[kk * 140 + pb];
            float4 b1 = *(const float4*)&Bs[kk * 140 + pb + 4];
            float a[8]  = {a0.x, a0.y, a0.z, a0.w, a1.x, a1.y, a1.z, a1.w};
            float bb[8] = {b0.x, b0.y, b0.z, b0.w, b1.x, b1.y, b1.z, b1.w};
#pragma unroll
            for (int i = 0; i < 8; ++i)
#pragma unroll
                for (int j = 0; j < 8; ++j)
                    acc[i][j] = fmaf(a[i], bb[j], acc[i][j]);
        }
    }

    const int gcol  = n0 >> 10;              // gate for this whole block-column
    const int qbase = (n0 & 1023) + tx * 8;  // 4b+u base
    const int j0 = n0 + tx * 8;
    float bsv[8];
#pragma unroll
    for (int j = 0; j < 8; ++j) bsv[j] = bias1[j0 + j] + bias2[j0 + j];
#pragma unroll
    for (int i = 0; i < 8; ++i) {
        const size_t rowoff = (size_t)(m0 + ty * 8 + i) * 4096;
#pragma unroll
        for (int jj = 0; jj < 8; ++jj) {
            const int q = qbase + jj;
            C[rowoff + ((q >> 2) << 4) + (gcol << 2) + (q & 3)] = acc[i][jj] + bsv[jj];
        }
    }
}

// ---------------------------------------------------------------------------
// Fused layer-pipelined LSTM recurrence.
// 256 blocks x 256 threads, plain launch; __launch_bounds__(256,1) + 256
// blocks on 256 CUs => all blocks co-resident, spin-waits make progress.
// Tick tau: layer0 step tau, layer1 step tau-1.
//
// TRANSPORT (per-producer tag, data separate — keeps regalloc identical to
// the verified barrier kernel): at end of tick tau, block b's wave 0 stores
// its 16 h floats (relaxed agent atomics, plain float slots), drains
// s_waitcnt vmcnt(0) (stores ack'd at LLC), then ONE lane publishes
// tag[tau&1][b] = tau+2. Consumers: thread t spin-polls tag of producer t
// only (1 dword, 1 live register), then __syncthreads() — all 256 tags
// observed by the block implies every producer's data is at the LLC — then
// the old verified 16x4B guaranteed-ready atomic-load staging runs
// unchanged. Critical path per tick: producer drain + one tag RT + one
// data RT, vs the old barrier's 4 serialized round trips.
//
// Ring-of-2 safety (unchanged argument): tag[tau&1][b]=tau+2 is written
// after block b finished its tick-tau staging reads; a buffer is only
// overwritten at tick tau+2 by a producer that saw ALL tags >= tau+2,
// i.e. every block finished reading it. Tags are monotonic per slot
// (memset re-zeroes before each replay), so no ABA.
// ---------------------------------------------------------------------------
__global__ void __launch_bounds__(256, 1) lstm_fused(
    const float* __restrict__ W_hh,  // [2][4096][1024]
    const float* __restrict__ W_ih,  // [2][4096][1024]
    const float* __restrict__ b_ih,  // [2][4096]
    const float* __restrict__ b_hh,  // [2][4096]
    const float* __restrict__ G,     // [2 br][T][4096] permuted layer-0 preacts
    const float* __restrict__ h1_0, const float* __restrict__ c1_0,
    const float* __restrict__ h2_0, const float* __restrict__ c2_0,
    float* hbf,                      // [2 buf][2 layer][2 br][1024] h ring
                                     //   (low 8KB doubles as o_out)
    uint32_t* tag)                   // [2 buf][256 producers]
{
    const int b = blockIdx.x, t = threadIdx.x;
    const int row = t & 15, slice = t >> 4;
    const int gate = row >> 2, uoff = row & 3;
    const int j_glob = gate * 1024 + b * 4 + uoff;

    // ---- weights -> registers (rotated to match LDS traversal) ----
    float4 w0[16], w1h[16], w1i[16];
    {
        const float* r0 = W_hh + (size_t)j_glob * 1024 + slice * 64;
        const float* r1 = W_hh + 4194304ull + (size_t)j_glob * 1024 + slice * 64;
        const float* r2 = W_ih + 4194304ull + (size_t)j_glob * 1024 + slice * 64;
#pragma unroll
        for (int m = 0; m < 16; ++m) {
            const int o = ((m + slice) & 15) << 2;
            w0[m]  = *(const float4*)(r0 + o);
            w1h[m] = *(const float4*)(r1 + o);
            w1i[m] = *(const float4*)(r2 + o);
        }
    }

    __shared__ float hs[4096];        // [4 vec][1024]
    __shared__ float red[4][4][16];   // [wave][acc][row]
    __shared__ float bl1s[16];        // layer-1 bias for owned rows

    float creg = 0.f;
    if (t < 16) {
        const int layer = t >> 3, br = (t >> 2) & 1, u = t & 3;
        const float* cc = br ? c2_0 : c1_0;
        const float* hh = br ? h2_0 : h1_0;
        creg = cc[layer * 1024 + b * 4 + u];
        const float hinit = hh[layer * 1024 + b * 4 + u];
        // init h -> buffer1 (consumed at tick 0)
        __hip_atomic_store(hbf + 4096 + layer * 2048 + br * 1024 + b * 4 + u,
                           hinit, __ATOMIC_RELAXED, __HIP_MEMORY_SCOPE_AGENT);
        // layer-1 init also -> buffer0 (consumed at tick 1; layer-1 is
        // inactive at tick 0 so nothing else writes these slots; covered
        // by tag[0][b]=2 published at end of tick 0, after these stores).
        if (layer == 1)
            __hip_atomic_store(hbf + 2048 + br * 1024 + b * 4 + u,
                               hinit, __ATOMIC_RELAXED, __HIP_MEMORY_SCOPE_AGENT);
    }
    if (t >= 32 && t < 48) {
        const int rr = t & 15;
        const int jj = 4096 + (rr >> 2) * 1024 + b * 4 + (rr & 3);
        bl1s[rr] = b_ih[jj] + b_hh[jj];
    }
    if (t < 64) {
        asm volatile("s_waitcnt vmcnt(0)" ::: "memory");  // init h at LLC
        if (t == 0)
            __hip_atomic_store(tag + 256 + b, 1u,
                               __ATOMIC_RELAXED, __HIP_MEMORY_SCOPE_AGENT);
    }
    __syncthreads();

    for (int tick = 0; tick <= T_SEQ; ++tick) {
        // ---- layer-0 G prefetch first (latency hidden under the tag poll) ----
        float gpre = 0.f;
        if (t < 32) {
            const int br = t >> 4, rr = t & 15;
            const int st = (tick < T_SEQ) ? tick : (T_SEQ - 1);
            gpre = G[((size_t)br * T_SEQ + st) * 4096 + b * 16 + rr];
        }

        // ---- wait for producer t's tag (1 dword, 1 live reg) ----
        {
            const uint32_t want = (uint32_t)tick + 1u;
            const uint32_t* tg = tag + ((tick + 1) & 1) * 256 + t;
            while (__hip_atomic_load(tg, __ATOMIC_RELAXED,
                                     __HIP_MEMORY_SCOPE_AGENT) < want)
                __builtin_amdgcn_s_sleep(1);
        }
        __syncthreads();   // block saw all 256 tags -> all h data at LLC

        // ---- stage h_prev: guaranteed-ready batched atomic loads ----
        {
            const float* src = hbf + ((tick + 1) & 1) * 4096;
            float v[16];
#pragma unroll
            for (int r = 0; r < 16; ++r)
                v[r] = __hip_atomic_load(src + t + r * 256, __ATOMIC_RELAXED,
                                         __HIP_MEMORY_SCOPE_AGENT);
#pragma unroll
            for (int r = 0; r < 16; ++r)
                hs[t + r * 256] = v[r];
        }
        __syncthreads();

        // ---- 3 matvecs over owned rows ----
        float a00 = 0.f, a01 = 0.f, a10 = 0.f, a11 = 0.f;
        const float4* H00 = (const float4*)hs;
        const float4* H01 = (const float4*)(hs + 1024);
        const float4* H10 = (const float4*)(hs + 2048);
        const float4* H11 = (const float4*)(hs + 3072);
#pragma unroll
        for (int m = 0; m < 16; ++m) {
            const int ci = (slice << 4) + ((m + slice) & 15);
            const float4 x0 = H00[ci], x1 = H01[ci];
            const float4 y0 = H10[ci], y1 = H11[ci];
            a00 = fmaf(w0[m].x, x0.x, a00); a00 = fmaf(w0[m].y, x0.y, a00);
            a00 = fmaf(w0[m].z, x0.z, a00); a00 = fmaf(w0[m].w, x0.w, a00);
            a01 = fmaf(w0[m].x, x1.x, a01); a01 = fmaf(w0[m].y, x1.y, a01);
            a01 = fmaf(w0[m].z, x1.z, a01); a01 = fmaf(w0[m].w, x1.w, a01);
            a10 = fmaf(w1i[m].x, x0.x, a10); a10 = fmaf(w1i[m].y, x0.y, a10);
            a10 = fmaf(w1i[m].z, x0.z, a10); a10 = fmaf(w1i[m].w, x0.w, a10);
            a10 = fmaf(w1h[m].x, y0.x, a10); a10 = fmaf(w1h[m].y, y0.y, a10);
            a10 = fmaf(w1h[m].z, y0.z, a10); a10 = fmaf(w1h[m].w, y0.w, a10);
            a11 = fmaf(w1i[m].x, x1.x, a11); a11 = fmaf(w1i[m].y, x1.y, a11);
            a11 = fmaf(w1i[m].z, x1.z, a11); a11 = fmaf(w1i[m].w, x1.w, a11);
            a11 = fmaf(w1h[m].x, y1.x, a11); a11 = fmaf(w1h[m].y, y1.y, a11);
            a11 = fmaf(w1h[m].z, y1.z, a11); a11 = fmaf(w1h[m].w, y1.w, a11);
        }
        a00 += __shfl_xor(a00, 16); a00 += __shfl_xor(a00, 32);
        a01 += __shfl_xor(a01, 16); a01 += __shfl_xor(a01, 32);
        a10 += __shfl_xor(a10, 16); a10 += __shfl_xor(a10, 32);
        a11 += __shfl_xor(a11, 16); a11 += __shfl_xor(a11, 32);
        const int wv = t >> 6, lane = t & 63;
        if (lane < 16) {
            red[wv][0][lane] = a00; red[wv][1][lane] = a01;
            red[wv][2][lane] = a10; red[wv][3][lane] = a11;
        }
        __syncthreads();

        // ---- tail: wave 0 only (red[] reuse is safe: other waves' next
        //      red-write sits behind the next post-staging __syncthreads,
        //      which waits for wave 0 to finish this tail) ----
        if (t < 64) {
            const int lb = t >> 4, rr = t & 15;
            float s = red[0][lb][rr] + red[1][lb][rr] + red[2][lb][rr] + red[3][lb][rr];
            s += (lb < 2) ? gpre : bl1s[rr];
            // lane lb*16+rr holds gate (rr>>2) of unit (rr&3), layer=lb>>1, br=lb&1
            const int src0 = ((t >> 2) << 4) + (t & 3);   // meaningful for t<16
            const float gi = __shfl(s, src0);
            const float gf = __shfl(s, src0 + 4);
            const float gg = __shfl(s, src0 + 8);
            const float go = __shfl(s, src0 + 12);
            if (t < 16) {
                const int layer = t >> 3, br = (t >> 2) & 1, u = t & 3;
                const bool active = (layer == 0) ? (tick < T_SEQ) : (tick >= 1);
                if (active) {
                    const float c = sigm(gf) * creg + sigm(gi) * tanhf(gg);
                    const float h = sigm(go) * tanhf(c);
                    creg = c;
                    if (layer == 1 && tick == T_SEQ) {
                        // final output -> dead low 8KB of the ring (buffer0
                        // layer-0 slots; our tick-T_SEQ staging saw all tags
                        // == T_SEQ+1, so every block finished its buffer0
                        // reads; nothing stages buffer0 after this).
                        __hip_atomic_store(hbf + br * 1024 + b * 4 + u, h,
                                           __ATOMIC_RELAXED, __HIP_MEMORY_SCOPE_AGENT);
                    } else {
                        __hip_atomic_store(
                            hbf + (tick & 1) * 4096 + layer * 2048 + br * 1024 + b * 4 + u,
                            h, __ATOMIC_RELAXED, __HIP_MEMORY_SCOPE_AGENT);
                    }
                }
            }
            if (tick < T_SEQ) {
                asm volatile("s_waitcnt vmcnt(0)" ::: "memory");  // h at LLC
                if (t == 0)
                    __hip_atomic_store(tag + (tick & 1) * 256 + b,
                                       (uint32_t)(tick + 2),
                                       __ATOMIC_RELAXED, __HIP_MEMORY_SCOPE_AGENT);
            }
        }
        // no end-of-loop barrier needed: this tick's hs reads completed
        // before the red-barrier above; next staging may overwrite hs freely.
    }
}

// ---------------------------------------------------------------------------
// out = 5*exp(-sum |o1 - o2|)
// ---------------------------------------------------------------------------
__global__ void __launch_bounds__(256) dist_kernel(const float* __restrict__ o,
                                                   float* __restrict__ out)
{
    int t = threadIdx.x;
    float s = 0.f;
    for (int i = t; i < 1024; i += 256) s += fabsf(o[i] - o[i + 1024]);
#pragma unroll
    for (int off = 1; off < 64; off <<= 1) s += __shfl_xor(s, off);
    __shared__ float r[4];
    if ((t & 63) == 0) r[t >> 6] = s;
    __syncthreads();
    if (t == 0) out[0] = 5.0f * expf(-(r[0] + r[1] + r[2] + r[3]));
}

// ---------------------------------------------------------------------------
extern "C" void kernel_launch(void* const* d_in, const int* in_sizes, int n_in,
                              void* d_out, int out_size, void* d_ws, size_t ws_size,
                              hipStream_t stream) {
    const float* s1   = (const float*)d_in[0];
    const float* s2   = (const float*)d_in[1];
    const float* h1_0 = (const float*)d_in[2];
    const float* c1_0 = (const float*)d_in[3];
    const float* h2_0 = (const float*)d_in[4];
    const float* c2_0 = (const float*)d_in[5];
    const float* W_ih = (const float*)d_in[6];
    const float* W_hh = (const float*)d_in[7];
    const float* b_ih = (const float*)d_in[8];
    const float* b_hh = (const float*)d_in[9];

    uint8_t* w8 = (uint8_t*)d_ws;
    float* hbf     = (float*)w8;                 // 32 KB: [2][4096] h ring
                                                 //   (low 8 KB reused as o_out)
    uint32_t* tag  = (uint32_t*)(w8 + 32768);    // 2 KB: [2][256] producer tags
    float* G       = (float*)(w8 + 65536);       // 128 MB: [2][T][4096]

    hipMemsetAsync(d_ws, 0, 65536, stream);      // zero ring + tags

    // Phase 1: layer-0 input GEMM for both branches (permuted output)
    dim3 ggrid(32, 64);
    gemm_nt_bias<<<ggrid, 256, 0, stream>>>(s1, s2, W_ih, b_ih, b_hh, G);

    // Phase 2: fused recurrence — plain launch; co-residency guaranteed by
    // __launch_bounds__(256,1) with 256 blocks on 256 CUs.
    lstm_fused<<<dim3(256), dim3(256), 0, stream>>>(
        W_hh, W_ih, b_ih, b_hh, G, h1_0, c1_0, h2_0, c2_0, hbf, tag);

    // Phase 3: scalar output
    dist_kernel<<<1, 256, 0, stream>>>((const float*)d_ws, (float*)d_out);
}

// Round 5
// 28320.969 us; speedup vs baseline: 1.1652x; 1.0280x over previous
//
#include <hip/hip_runtime.h>
#include <math.h>
#include <stdint.h>

#define T_SEQ 4096

__device__ __forceinline__ float sigm(float x) { return 1.0f / (1.0f + expf(-x)); }

// ---------------------------------------------------------------------------
// fp32 NT GEMM with bias: layer-0 preactivations for both branches.
// C[m][p(j)] = sum_k A[m][k]*B[j][k] + bias1[j]+bias2[j]
// Column permutation p(j): j = gate*1024 + 4b+u  ->  b*16 + gate*4 + u, so
// each recurrence block's 16 gate preacts are one contiguous 64 B line.
// ---------------------------------------------------------------------------
__global__ void __launch_bounds__(256) gemm_nt_bias(
    const float* __restrict__ A0, const float* __restrict__ A1,
    const float* __restrict__ B,
    const float* __restrict__ bias1, const float* __restrict__ bias2,
    float* __restrict__ C)
{
    const int t  = threadIdx.x;
    const int tx = t & 15, ty = t >> 4;
    const int n0 = blockIdx.x * 128, m0 = blockIdx.y * 128;
    const float* Ab = (m0 < 4096) ? A0 : A1;
    const int ml0 = (m0 < 4096) ? m0 : (m0 - 4096);

    __shared__ float As[16 * 140];
    __shared__ float Bs[16 * 140];

    const int lr = t >> 1;
    const int lh = t & 1;
    const int pw = lr + ((lr >> 5) << 2);
    const int pa = ty * 8 + ((ty >> 2) << 2);
    const int pb = tx * 8 + ((tx >> 2) << 2);

    float acc[8][8];
#pragma unroll
    for (int i = 0; i < 8; ++i)
#pragma unroll
        for (int j = 0; j < 8; ++j) acc[i][j] = 0.f;

    for (int k0 = 0; k0 < 1024; k0 += 16) {
        const float* ap = Ab + (size_t)(ml0 + lr) * 1024 + k0 + lh * 8;
        float4 av0 = *(const float4*)ap;
        float4 av1 = *(const float4*)(ap + 4);
        const float* bp = B + (size_t)(n0 + lr) * 1024 + k0 + lh * 8;
        float4 bv0 = *(const float4*)bp;
        float4 bv1 = *(const float4*)(bp + 4);

        __syncthreads();
        const int kb = lh * 8;
        As[(kb + 0) * 140 + pw] = av0.x;  As[(kb + 1) * 140 + pw] = av0.y;
        As[(kb + 2) * 140 + pw] = av0.z;  As[(kb + 3) * 140 + pw] = av0.w;
        As[(kb + 4) * 140 + pw] = av1.x;  As[(kb + 5) * 140 + pw] = av1.y;
        As[(kb + 6) * 140 + pw] = av1.z;  As[(kb + 7) * 140 + pw] = av1.w;
        Bs[(kb + 0) * 140 + pw] = bv0.x;  Bs[(kb + 1) * 140 + pw] = bv0.y;
        Bs[(kb + 2) * 140 + pw] = bv0.z;  Bs[(kb + 3) * 140 + pw] = bv0.w;
        Bs[(kb + 4) * 140 + pw] = bv1.x;  Bs[(kb + 5) * 140 + pw] = bv1.y;
        Bs[(kb + 6) * 140 + pw] = bv1.z;  Bs[(kb + 7) * 140 + pw] = bv1.w;
        __syncthreads();

#pragma unroll
        for (int kk = 0; kk < 16; ++kk) {
            float4 a0 = *(const float4*)&As[kk * 140 + pa];
            float4 a1 = *(const float4*)&As[kk * 140 + pa + 4];
            float4 b0 = *(const float4*)&Bs[kk * 140 + pb];
            float4 b1 = *(const float4*)&Bs[kk * 140 + pb + 4];
            float a[8]  = {a0.x, a0.y, a0.z, a0.w, a1.x, a1.y, a1.z, a1.w};
            float bb[8] = {b0.x, b0.y, b0.z, b0.w, b1.x, b1.y, b1.z, b1.w};
#pragma unroll
            for (int i = 0; i < 8; ++i)
#pragma unroll
                for (int j = 0; j < 8; ++j)
                    acc[i][j] = fmaf(a[i], bb[j], acc[i][j]);
        }
    }

    const int gcol  = n0 >> 10;              // gate for this whole block-column
    const int qbase = (n0 & 1023) + tx * 8;  // 4b+u base
    const int j0 = n0 + tx * 8;
    float bsv[8];
#pragma unroll
    for (int j = 0; j < 8; ++j) bsv[j] = bias1[j0 + j] + bias2[j0 + j];
#pragma unroll
    for (int i = 0; i < 8; ++i) {
        const size_t rowoff = (size_t)(m0 + ty * 8 + i) * 4096;
#pragma unroll
        for (int jj = 0; jj < 8; ++jj) {
            const int q = qbase + jj;
            C[rowoff + ((q >> 2) << 4) + (gcol << 2) + (q & 3)] = acc[i][jj] + bsv[jj];
        }
    }
}

// ---------------------------------------------------------------------------
// Fused layer-pipelined LSTM recurrence.
// 256 blocks x 256 threads, plain launch; __launch_bounds__(256,1) + 256
// blocks on 256 CUs => all blocks co-resident, spin-waits make progress.
// Tick tau: layer0 step tau, layer1 step tau-1.
//
// TRANSPORT (per-producer tag, data separate): at end of tick tau, block
// b's wave 0 stores its 16 h floats (relaxed agent atomics, plain float
// slots), drains s_waitcnt vmcnt(0) (stores ack'd at LLC), then ONE lane
// publishes tag[tau&1][b] = tau+2. Consumers: thread t spin-polls tag of
// producer t only (1 dword, 1 live register), then __syncthreads() — all
// 256 tags observed by the block implies every producer's data is at the
// LLC — then 16x4B guaranteed-ready atomic-load staging. Critical path per
// tick: producer drain + one tag RT + one data RT.
//
// Ring-of-2 safety: tag[tau&1][b]=tau+2 is written after block b finished
// its tick-tau staging reads; a buffer is only overwritten at tick tau+2
// by a producer that saw ALL tags >= tau+2, i.e. every block finished
// reading it. Tags monotonic per slot (memset re-zeroes before each
// replay), so no ABA.
//
// REGISTER PINNING (R3/R4 lesson): at VGPR=128 the allocator sank the
// 192-VGPR weight arrays' loads into the tick loop -> ~50 MB/tick LLC
// re-reads -> 29 ms. float4 is a struct (asm would pass it indirectly,
// unsupported tied), so we pin PER SCALAR COMPONENT: empty asm with "+v"
// on each of the 12 floats of w0/w1h/w1i[m], statically unrolled. Each
// scalar becomes an opaque register value the compiler must keep live —
// loads cannot be sunk into the loop or rematerialized.
// ---------------------------------------------------------------------------
__global__ void __launch_bounds__(256, 1) lstm_fused(
    const float* __restrict__ W_hh,  // [2][4096][1024]
    const float* __restrict__ W_ih,  // [2][4096][1024]
    const float* __restrict__ b_ih,  // [2][4096]
    const float* __restrict__ b_hh,  // [2][4096]
    const float* __restrict__ G,     // [2 br][T][4096] permuted layer-0 preacts
    const float* __restrict__ h1_0, const float* __restrict__ c1_0,
    const float* __restrict__ h2_0, const float* __restrict__ c2_0,
    float* hbf,                      // [2 buf][2 layer][2 br][1024] h ring
                                     //   (low 8KB doubles as o_out)
    uint32_t* tag)                   // [2 buf][256 producers]
{
    const int b = blockIdx.x, t = threadIdx.x;
    const int row = t & 15, slice = t >> 4;
    const int gate = row >> 2, uoff = row & 3;
    const int j_glob = gate * 1024 + b * 4 + uoff;

    // ---- weights -> registers (rotated to match LDS traversal) ----
    float4 w0[16], w1h[16], w1i[16];
    {
        const float* r0 = W_hh + (size_t)j_glob * 1024 + slice * 64;
        const float* r1 = W_hh + 4194304ull + (size_t)j_glob * 1024 + slice * 64;
        const float* r2 = W_ih + 4194304ull + (size_t)j_glob * 1024 + slice * 64;
#pragma unroll
        for (int m = 0; m < 16; ++m) {
            const int o = ((m + slice) & 15) << 2;
            w0[m]  = *(const float4*)(r0 + o);
            w1h[m] = *(const float4*)(r1 + o);
            w1i[m] = *(const float4*)(r2 + o);
        }
    }
    // Pin all 192 weight scalars into VGPRs (see header comment).
#pragma unroll
    for (int m = 0; m < 16; ++m)
        asm volatile(""
            : "+v"(w0[m].x),  "+v"(w0[m].y),  "+v"(w0[m].z),  "+v"(w0[m].w),
              "+v"(w1h[m].x), "+v"(w1h[m].y), "+v"(w1h[m].z), "+v"(w1h[m].w),
              "+v"(w1i[m].x), "+v"(w1i[m].y), "+v"(w1i[m].z), "+v"(w1i[m].w));

    __shared__ float hs[4096];        // [4 vec][1024]
    __shared__ float red[4][4][16];   // [wave][acc][row]
    __shared__ float bl1s[16];        // layer-1 bias for owned rows

    float creg = 0.f;
    if (t < 16) {
        const int layer = t >> 3, br = (t >> 2) & 1, u = t & 3;
        const float* cc = br ? c2_0 : c1_0;
        const float* hh = br ? h2_0 : h1_0;
        creg = cc[layer * 1024 + b * 4 + u];
        const float hinit = hh[layer * 1024 + b * 4 + u];
        // init h -> buffer1 (consumed at tick 0)
        __hip_atomic_store(hbf + 4096 + layer * 2048 + br * 1024 + b * 4 + u,
                           hinit, __ATOMIC_RELAXED, __HIP_MEMORY_SCOPE_AGENT);
        // layer-1 init also -> buffer0 (consumed at tick 1; layer-1 is
        // inactive at tick 0 so nothing else writes these slots; covered
        // by tag[0][b]=2 published at end of tick 0, after these stores).
        if (layer == 1)
            __hip_atomic_store(hbf + 2048 + br * 1024 + b * 4 + u,
                               hinit, __ATOMIC_RELAXED, __HIP_MEMORY_SCOPE_AGENT);
    }
    if (t >= 32 && t < 48) {
        const int rr = t & 15;
        const int jj = 4096 + (rr >> 2) * 1024 + b * 4 + (rr & 3);
        bl1s[rr] = b_ih[jj] + b_hh[jj];
    }
    if (t < 64) {
        asm volatile("s_waitcnt vmcnt(0)" ::: "memory");  // init h at LLC
        if (t == 0)
            __hip_atomic_store(tag + 256 + b, 1u,
                               __ATOMIC_RELAXED, __HIP_MEMORY_SCOPE_AGENT);
    }
    __syncthreads();

    for (int tick = 0; tick <= T_SEQ; ++tick) {
        // ---- layer-0 G prefetch first (latency hidden under the tag poll) ----
        float gpre = 0.f;
        if (t < 32) {
            const int br = t >> 4, rr = t & 15;
            const int st = (tick < T_SEQ) ? tick : (T_SEQ - 1);
            gpre = G[((size_t)br * T_SEQ + st) * 4096 + b * 16 + rr];
        }

        // ---- wait for producer t's tag (1 dword, 1 live reg) ----
        {
            const uint32_t want = (uint32_t)tick + 1u;
            const uint32_t* tg = tag + ((tick + 1) & 1) * 256 + t;
            while (__hip_atomic_load(tg, __ATOMIC_RELAXED,
                                     __HIP_MEMORY_SCOPE_AGENT) < want)
                __builtin_amdgcn_s_sleep(1);
        }
        __syncthreads();   // block saw all 256 tags -> all h data at LLC

        // ---- stage h_prev: guaranteed-ready batched atomic loads ----
        {
            const float* src = hbf + ((tick + 1) & 1) * 4096;
            float v[16];
#pragma unroll
            for (int r = 0; r < 16; ++r)
                v[r] = __hip_atomic_load(src + t + r * 256, __ATOMIC_RELAXED,
                                         __HIP_MEMORY_SCOPE_AGENT);
#pragma unroll
            for (int r = 0; r < 16; ++r)
                hs[t + r * 256] = v[r];
        }
        __syncthreads();

        // ---- 3 matvecs over owned rows ----
        float a00 = 0.f, a01 = 0.f, a10 = 0.f, a11 = 0.f;
        const float4* H00 = (const float4*)hs;
        const float4* H01 = (const float4*)(hs + 1024);
        const float4* H10 = (const float4*)(hs + 2048);
        const float4* H11 = (const float4*)(hs + 3072);
#pragma unroll
        for (int m = 0; m < 16; ++m) {
            const int ci = (slice << 4) + ((m + slice) & 15);
            const float4 x0 = H00[ci], x1 = H01[ci];
            const float4 y0 = H10[ci], y1 = H11[ci];
            a00 = fmaf(w0[m].x, x0.x, a00); a00 = fmaf(w0[m].y, x0.y, a00);
            a00 = fmaf(w0[m].z, x0.z, a00); a00 = fmaf(w0[m].w, x0.w, a00);
            a01 = fmaf(w0[m].x, x1.x, a01); a01 = fmaf(w0[m].y, x1.y, a01);
            a01 = fmaf(w0[m].z, x1.z, a01); a01 = fmaf(w0[m].w, x1.w, a01);
            a10 = fmaf(w1i[m].x, x0.x, a10); a10 = fmaf(w1i[m].y, x0.y, a10);
            a10 = fmaf(w1i[m].z, x0.z, a10); a10 = fmaf(w1i[m].w, x0.w, a10);
            a10 = fmaf(w1h[m].x, y0.x, a10); a10 = fmaf(w1h[m].y, y0.y, a10);
            a10 = fmaf(w1h[m].z, y0.z, a10); a10 = fmaf(w1h[m].w, y0.w, a10);
            a11 = fmaf(w1i[m].x, x1.x, a11); a11 = fmaf(w1i[m].y, x1.y, a11);
            a11 = fmaf(w1i[m].z, x1.z, a11); a11 = fmaf(w1i[m].w, x1.w, a11);
            a11 = fmaf(w1h[m].x, y1.x, a11); a11 = fmaf(w1h[m].y, y1.y, a11);
            a11 = fmaf(w1h[m].z, y1.z, a11); a11 = fmaf(w1h[m].w, y1.w, a11);
        }
        a00 += __shfl_xor(a00, 16); a00 += __shfl_xor(a00, 32);
        a01 += __shfl_xor(a01, 16); a01 += __shfl_xor(a01, 32);
        a10 += __shfl_xor(a10, 16); a10 += __shfl_xor(a10, 32);
        a11 += __shfl_xor(a11, 16); a11 += __shfl_xor(a11, 32);
        const int wv = t >> 6, lane = t & 63;
        if (lane < 16) {
            red[wv][0][lane] = a00; red[wv][1][lane] = a01;
            red[wv][2][lane] = a10; red[wv][3][lane] = a11;
        }
        __syncthreads();

        // ---- tail: wave 0 only (red[] reuse is safe: other waves' next
        //      red-write sits behind the next post-staging __syncthreads,
        //      which waits for wave 0 to finish this tail) ----
        if (t < 64) {
            const int lb = t >> 4, rr = t & 15;
            float s = red[0][lb][rr] + red[1][lb][rr] + red[2][lb][rr] + red[3][lb][rr];
            s += (lb < 2) ? gpre : bl1s[rr];
            // lane lb*16+rr holds gate (rr>>2) of unit (rr&3), layer=lb>>1, br=lb&1
            const int src0 = ((t >> 2) << 4) + (t & 3);   // meaningful for t<16
            const float gi = __shfl(s, src0);
            const float gf = __shfl(s, src0 + 4);
            const float gg = __shfl(s, src0 + 8);
            const float go = __shfl(s, src0 + 12);
            if (t < 16) {
                const int layer = t >> 3, br = (t >> 2) & 1, u = t & 3;
                const bool active = (layer == 0) ? (tick < T_SEQ) : (tick >= 1);
                if (active) {
                    const float c = sigm(gf) * creg + sigm(gi) * tanhf(gg);
                    const float h = sigm(go) * tanhf(c);
                    creg = c;
                    if (layer == 1 && tick == T_SEQ) {
                        // final output -> dead low 8KB of the ring (buffer0
                        // layer-0 slots; our tick-T_SEQ staging saw all tags
                        // == T_SEQ+1, so every block finished its buffer0
                        // reads; nothing stages buffer0 after this).
                        __hip_atomic_store(hbf + br * 1024 + b * 4 + u, h,
                                           __ATOMIC_RELAXED, __HIP_MEMORY_SCOPE_AGENT);
                    } else {
                        __hip_atomic_store(
                            hbf + (tick & 1) * 4096 + layer * 2048 + br * 1024 + b * 4 + u,
                            h, __ATOMIC_RELAXED, __HIP_MEMORY_SCOPE_AGENT);
                    }
                }
            }
            if (tick < T_SEQ) {
                asm volatile("s_waitcnt vmcnt(0)" ::: "memory");  // h at LLC
                if (t == 0)
                    __hip_atomic_store(tag + (tick & 1) * 256 + b,
                                       (uint32_t)(tick + 2),
                                       __ATOMIC_RELAXED, __HIP_MEMORY_SCOPE_AGENT);
            }
        }
        // no end-of-loop barrier needed: this tick's hs reads completed
        // before the red-barrier above; next staging may overwrite hs freely.
    }
}

// ---------------------------------------------------------------------------
// out = 5*exp(-sum |o1 - o2|)
// ---------------------------------------------------------------------------
__global__ void __launch_bounds__(256) dist_kernel(const float* __restrict__ o,
                                                   float* __restrict__ out)
{
    int t = threadIdx.x;
    float s = 0.f;
    for (int i = t; i < 1024; i += 256) s += fabsf(o[i] - o[i + 1024]);
#pragma unroll
    for (int off = 1; off < 64; off <<= 1) s += __shfl_xor(s, off);
    __shared__ float r[4];
    if ((t & 63) == 0) r[t >> 6] = s;
    __syncthreads();
    if (t == 0) out[0] = 5.0f * expf(-(r[0] + r[1] + r[2] + r[3]));
}

// ---------------------------------------------------------------------------
extern "C" void kernel_launch(void* const* d_in, const int* in_sizes, int n_in,
                              void* d_out, int out_size, void* d_ws, size_t ws_size,
                              hipStream_t stream) {
    const float* s1   = (const float*)d_in[0];
    const float* s2   = (const float*)d_in[1];
    const float* h1_0 = (const float*)d_in[2];
    const float* c1_0 = (const float*)d_in[3];
    const float* h2_0 = (const float*)d_in[4];
    const float* c2_0 = (const float*)d_in[5];
    const float* W_ih = (const float*)d_in[6];
    const float* W_hh = (const float*)d_in[7];
    const float* b_ih = (const float*)d_in[8];
    const float* b_hh = (const float*)d_in[9];

    uint8_t* w8 = (uint8_t*)d_ws;
    float* hbf     = (float*)w8;                 // 32 KB: [2][4096] h ring
                                                 //   (low 8 KB reused as o_out)
    uint32_t* tag  = (uint32_t*)(w8 + 32768);    // 2 KB: [2][256] producer tags
    float* G       = (float*)(w8 + 65536);       // 128 MB: [2][T][4096]

    hipMemsetAsync(d_ws, 0, 65536, stream);      // zero ring + tags

    // Phase 1: layer-0 input GEMM for both branches (permuted output)
    dim3 ggrid(32, 64);
    gemm_nt_bias<<<ggrid, 256, 0, stream>>>(s1, s2, W_ih, b_ih, b_hh, G);

    // Phase 2: fused recurrence — plain launch; co-residency guaranteed by
    // __launch_bounds__(256,1) with 256 blocks on 256 CUs.
    lstm_fused<<<dim3(256), dim3(256), 0, stream>>>(
        W_hh, W_ih, b_ih, b_hh, G, h1_0, c1_0, h2_0, c2_0, hbf, tag);

    // Phase 3: scalar output
    dist_kernel<<<1, 256, 0, stream>>>((const float*)d_ws, (float*)d_out);
}